// Round 16
// baseline (463.011 us; speedup 1.0000x reference)
//
#include <hip/hip_runtime.h>
#include <math.h>

#define NSTEPS 128
#define BATCH  32768
#define HID    64

constexpr float DTf = 1.0f / 128.0f;
constexpr float TWO_LOG2E = 2.88539008177792681f;

typedef float v2f __attribute__((ext_vector_type(2)));

__device__ __forceinline__ v2f v2ld(const float* p) { return *(const v2f*)p; }
__device__ __forceinline__ v2f bc(float s) { v2f r = {s, s}; return r; }
__device__ __forceinline__ v2f pkfma(v2f a, v2f b, v2f c) {
    return __builtin_elementwise_fma(a, b, c);
}

struct CD { float c, dre, dim; };

__device__ __forceinline__ float fast_tanh(float x) {
    float e = __builtin_amdgcn_exp2f(x * TWO_LOG2E);
    return 1.0f - 2.0f * __builtin_amdgcn_rcpf(e + 1.0f);
}
__device__ __forceinline__ v2f fast_tanh2(v2f z) {
    v2f zs = z * TWO_LOG2E;
    v2f e;
    e.x = __builtin_amdgcn_exp2f(zs.x);
    e.y = __builtin_amdgcn_exp2f(zs.y);
    v2f e1 = e + 1.0f;
    v2f r;
    r.x = __builtin_amdgcn_rcpf(e1.x);
    r.y = __builtin_amdgcn_rcpf(e1.y);
    return pkfma(bc(-2.0f), r, bc(1.0f));
}

// ---- grad MLP: 5 -> 64 -> 6, packed pairs ----
__device__ __forceinline__ void grad_mlp(
    float n, float x0, float x1, float x2, float p,
    const float* __restrict__ w1, const float* __restrict__ b1,
    const float* __restrict__ w2, const float* __restrict__ b2,
    float& og0, float& og1, float& og2, float& og3, float& og4, float& og5)
{
    v2f og01 = { b2[0], b2[1] };
    v2f og23 = { b2[2], b2[3] };
    v2f og45 = { b2[4], b2[5] };
#pragma unroll 4
    for (int j = 0; j < HID; j += 2) {
        v2f z = pkfma(bc(n),  v2ld(w1 + j),
                pkfma(bc(x0), v2ld(w1 + HID   + j),
                pkfma(bc(x1), v2ld(w1 + 2*HID + j),
                pkfma(bc(x2), v2ld(w1 + 3*HID + j),
                pkfma(bc(p),  v2ld(w1 + 4*HID + j), v2ld(b1 + j))))));
        v2f h = fast_tanh2(z);
        const float* wj = w2 + j*6;
        og01 = pkfma(bc(h.x), v2ld(wj),     pkfma(bc(h.y), v2ld(wj + 6),  og01));
        og23 = pkfma(bc(h.x), v2ld(wj + 2), pkfma(bc(h.y), v2ld(wj + 8),  og23));
        og45 = pkfma(bc(h.x), v2ld(wj + 4), pkfma(bc(h.y), v2ld(wj + 10), og45));
    }
    og0 = og01.x; og1 = og01.y; og2 = og23.x;
    og3 = og23.y; og4 = og45.x; og5 = og45.y;
}

// ---- jump MLP, double-sided ----
template<bool USE_TD>
__device__ __forceinline__ void jump_mlp(
    float n, float x0, float x1, float x2, float p,
    const float* __restrict__ v1, const float* __restrict__ c1,
    const float* __restrict__ vw2, const float* __restrict__ Td,
    float& dup0, float& dup1, float& dum0, float& dum1)
{
    v2f dup01 = { 0.f, 0.f };
    v2f dum01 = { 0.f, 0.f };
#pragma unroll 4
    for (int j = 0; j < HID; j += 2) {
        v2f d  = v2ld(v1 + j);
        v2f zb = pkfma(bc(n), d,
                 pkfma(bc(x0), v2ld(v1 + HID   + j),
                 pkfma(bc(x1), v2ld(v1 + 2*HID + j),
                 pkfma(bc(x2), v2ld(v1 + 3*HID + j),
                 pkfma(bc(p),  v2ld(v1 + 4*HID + j), v2ld(c1 + j))))));
        v2f T  = fast_tanh2(zb);
        v2f Tv;
        if (USE_TD) Tv = v2ld(Td + j);
        else { Tv.x = fast_tanh(d.x); Tv.y = fast_tanh(d.y); }
        v2f a    = T * Tv;
        v2f oma2 = pkfma(-a, a, bc(1.0f));
        v2f r;
        r.x = __builtin_amdgcn_rcpf(oma2.x);
        r.y = __builtin_amdgcn_rcpf(oma2.y);
        v2f s1 = (T + Tv) * r;
        v2f u1 = s1 - T;
        v2f ep = pkfma(-s1, a, u1);
        v2f s2 = (T - Tv) * r;
        v2f u2 = s2 - T;
        v2f em = pkfma(s2, a, u2);
        v2f wv0 = v2ld(vw2 + 2*j);
        v2f wv1 = v2ld(vw2 + 2*j + 2);
        dup01 = pkfma(bc(ep.x), wv0, pkfma(bc(ep.y), wv1, dup01));
        dum01 = pkfma(bc(em.x), wv0, pkfma(bc(em.y), wv1, dum01));
    }
    dup0 = dup01.x; dup1 = dup01.y;
    dum0 = dum01.x; dum1 = dum01.y;
}

// ---- jump MLP, single-sided: e = tanh(zb + sgn*d) - tanh(zb) ----
__device__ __forceinline__ void jump_mlp_1s(
    float n, float x0, float x1, float x2, float p, float sgn,
    const float* __restrict__ v1, const float* __restrict__ c1,
    const float* __restrict__ vw2, const float* __restrict__ Td,
    float& e0, float& e1)
{
    v2f acc = { 0.f, 0.f };
#pragma unroll 4
    for (int j = 0; j < HID; j += 2) {
        v2f d  = v2ld(v1 + j);
        v2f zb = pkfma(bc(n), d,
                 pkfma(bc(x0), v2ld(v1 + HID   + j),
                 pkfma(bc(x1), v2ld(v1 + 2*HID + j),
                 pkfma(bc(x2), v2ld(v1 + 3*HID + j),
                 pkfma(bc(p),  v2ld(v1 + 4*HID + j), v2ld(c1 + j))))));
        v2f T   = fast_tanh2(zb);
        v2f Tsv = bc(sgn) * v2ld(Td + j);
        v2f as  = T * Tsv;
        v2f oma = pkfma(-as, as, bc(1.0f));
        v2f r;
        r.x = __builtin_amdgcn_rcpf(oma.x);
        r.y = __builtin_amdgcn_rcpf(oma.y);
        v2f s1 = (T + Tsv) * r;
        v2f u1 = s1 - T;
        v2f e  = pkfma(-s1, as, u1);
        acc = pkfma(bc(e.x), v2ld(vw2 + 2*j), pkfma(bc(e.y), v2ld(vw2 + 2*j + 2), acc));
    }
    e0 = acc.x; e1 = acc.y;
}

// Full step (fallback path only)
template<bool USE_TD>
__device__ __forceinline__ CD step_core(
    float n, float x0, float x1, float x2, float p, float t,
    float db0, float db1, float db2, float dN, float phi,
    const float* __restrict__ w1, const float* __restrict__ b1,
    const float* __restrict__ w2, const float* __restrict__ b2,
    const float* __restrict__ v1, const float* __restrict__ c1,
    const float* __restrict__ vw2, const float* __restrict__ Td)
{
    float og0, og1, og2, og3, og4, og5;
    grad_mlp(n,x0,x1,x2,p, w1,b1,w2,b2, og0,og1,og2,og3,og4,og5);
    float dup0, dup1, dum0, dum1;
    jump_mlp<USE_TD>(n,x0,x1,x2,p, v1,c1,vw2,Td, dup0,dup1,dum0,dum1);

    float r2    = fmaf(x0,x0, fmaf(x1,x1, x2*x2));
    float gamma = 0.1f - (0.5f + 0.1f*r2) * __builtin_amdgcn_rcpf(1.0f + r2);
    float xdb   = fmaf(x0,db0, fmaf(x1,db1, x2*db2));
    float kc    = sqrtf(fmaf(0.2f, fabsf(n), 1.0f));
    float gdb_r = fmaf(og0,db0, fmaf(og1,db1, og2*db2));
    float gdb_i = fmaf(og3,db0, fmaf(og4,db1, og5*db2));
    float gx_r  = fmaf(og0,x0,  fmaf(og1,x1,  og2*x2));
    float gx_i  = fmaf(og3,x0,  fmaf(og4,x1,  og5*x2));
    float gb_r  = kc * fmaf(gamma*xdb, gx_r, 0.5f*gdb_r);
    float gb_i  = kc * fmaf(gamma*xdb, gx_i, 0.5f*gdb_i);

    float alpha = 0.5f*(n + 1.0f);
    float beta  = fmaf(0.4f, fabsf(n), 0.1f);
    float cf    = 0.1f*(1.0f + t)*DTf;
    float d0r = gb_r - (alpha*dup0 + beta*dum0)*DTf - cf*(og0+og1+og2);
    float d0i = gb_i - (alpha*dup1 + beta*dum1)*DTf - cf*(og3+og4+og5);

    float c, sr, si;
    if (dN > 0.5f)       { c = 1.0f;          sr = dup0; si = dup1; }
    else if (dN < -0.5f) { c = 1.0f;          sr = dum0; si = dum1; }
    else                 { c = 1.0f - p*DTf;  sr = d0r;  si = d0i;  }

    float sp, cp;
    __sincosf(phi, &sp, &cp);
    CD o;
    o.c   = c;
    o.dre = fmaf(cp, sr,  sp*si);
    o.dim = fmaf(cp, si, -sp*sr);
    return o;
}

__device__ __forceinline__ void mlp_u0(
    float n, float x0, float x1, float x2, float p,
    const float* __restrict__ w1, const float* __restrict__ b1,
    const float* __restrict__ w2, const float* __restrict__ b2,
    float& ur, float& ui)
{
    v2f o01 = { b2[0], b2[1] };
#pragma unroll 4
    for (int j = 0; j < HID; j += 2) {
        v2f z = pkfma(bc(n),  v2ld(w1 + j),
                pkfma(bc(x0), v2ld(w1 + HID   + j),
                pkfma(bc(x1), v2ld(w1 + 2*HID + j),
                pkfma(bc(x2), v2ld(w1 + 3*HID + j),
                pkfma(bc(p),  v2ld(w1 + 4*HID + j), v2ld(b1 + j))))));
        v2f h = fast_tanh2(z);
        o01 = pkfma(bc(h.x), v2ld(w2 + 2*j), pkfma(bc(h.y), v2ld(w2 + 2*j + 2), o01));
    }
    ur = o01.x; ui = o01.y;
}

// ---- Pass 1: phi prefix ----
__global__ void __launch_bounds__(256) k_phi(
    const float* __restrict__ X, const float* __restrict__ P,
    float* __restrict__ phi, float* __restrict__ phiF)
{
    int b = blockIdx.x*256 + threadIdx.x;
    double s = 0.0;
    for (int k = 0; k < NSTEPS; k++) {
        size_t idx = (size_t)k*BATCH + b;
        phi[idx] = (float)(DTf * s);
        float p = P[idx];
        const float* xp = X + idx*3;
        float x0 = xp[0], x1 = xp[1], x2 = xp[2];
        s += (double)p * (double)(x0*x0 + x1*x1 + x2*x2);
    }
    phiF[b] = (float)(DTf * s);
}

// ---- Pass 1b: classify tasks into per-k global lists (full / jump) ----
// List order is atomic-nondeterministic; content set is deterministic and
// every task's result is a pure function of its own data, written keyed by
// its original index -> output deterministic.
__global__ void __launch_bounds__(256) k_classify(
    const float* __restrict__ N,
    unsigned short* __restrict__ fullList, unsigned short* __restrict__ jumpList,
    int2* __restrict__ counters)
{
    int k   = blockIdx.y;
    int tid = threadIdx.x;
    int b   = blockIdx.x*256 + tid;

    __shared__ int cnt[2];
    __shared__ int gbase[2];
    __shared__ unsigned short lf[256], lj[256];
    if (tid == 0) { cnt[0] = 0; cnt[1] = 0; }
    __syncthreads();

    size_t i0 = (size_t)k*BATCH + b;
    float n0  = N[i0];
    float dN  = N[i0 + BATCH] - n0;            // exact +-1/0 in fp32
    if (dN == 0.0f) {
        int r = atomicAdd(&cnt[0], 1);
        lf[r] = (unsigned short)b;
    } else {
        int r = atomicAdd(&cnt[1], 1);
        lj[r] = (unsigned short)(b | (dN < 0.0f ? 0x8000 : 0));
    }
    __syncthreads();
    if (tid == 0) gbase[0] = atomicAdd(&counters[k].x, cnt[0]);
    if (tid == 1) gbase[1] = atomicAdd(&counters[k].y, cnt[1]);
    __syncthreads();
    if (tid < cnt[0]) fullList[(size_t)k*BATCH + gbase[0] + tid] = lf[tid];
    if (tid < cnt[1]) jumpList[(size_t)k*BATCH + gbase[1] + tid] = lj[tid];
}

// ---- Pass 2a: FULL tasks only (homogeneous blocks, no imbalance) ----
__global__ void __launch_bounds__(256) k_step_full(
    const float* __restrict__ N,  const float* __restrict__ X,
    const float* __restrict__ P,  const float* __restrict__ Tarr,
    const float* __restrict__ dB,
    const float* __restrict__ Wg1, const float* __restrict__ bg1,
    const float* __restrict__ Wg2, const float* __restrict__ bg2,
    const float* __restrict__ Wj1, const float* __restrict__ bj1,
    const float* __restrict__ Wj2, const float* __restrict__ bj2,
    const float* __restrict__ phiA,
    const unsigned short* __restrict__ fullList, const int2* __restrict__ counters,
    float2* __restrict__ dA)
{
    int k = blockIdx.y;
    int count = counters[k].x;
    int start = blockIdx.x*256;
    if (start >= count) return;

    const float* w1  = Wg1 + k*5*HID;
    const float* b1  = bg1 + k*HID;
    const float* w2  = Wg2 + k*HID*6;
    const float* b2  = bg2 + k*6;
    const float* v1  = Wj1 + k*5*HID;
    const float* c1  = bj1 + k*HID;
    const float* vw2 = Wj2 + k*HID*2;
    float t = Tarr[k];

    __shared__ float Td[HID];
    if (threadIdx.x < HID) Td[threadIdx.x] = fast_tanh(v1[threadIdx.x]);
    __syncthreads();

    int slot = start + threadIdx.x;
    bool act = slot < count;
    int ob   = fullList[(size_t)k*BATCH + (act ? slot : count - 1)];
    size_t idx = (size_t)k*BATCH + ob;
    float n = N[idx], p = P[idx];
    const float* xp  = X  + idx*3;
    const float* dbp = dB + idx*3;
    float x0 = xp[0],  x1 = xp[1],  x2 = xp[2];
    float db0 = dbp[0], db1 = dbp[1], db2 = dbp[2];
    float phi = phiA[idx];

    float dup0, dup1, dum0, dum1;
    jump_mlp<true>(n,x0,x1,x2,p, v1,c1,vw2,Td, dup0,dup1,dum0,dum1);
    float og0, og1, og2, og3, og4, og5;
    grad_mlp(n,x0,x1,x2,p, w1,b1,w2,b2, og0,og1,og2,og3,og4,og5);

    float r2    = fmaf(x0,x0, fmaf(x1,x1, x2*x2));
    float gamma = 0.1f - (0.5f + 0.1f*r2) * __builtin_amdgcn_rcpf(1.0f + r2);
    float xdb   = fmaf(x0,db0, fmaf(x1,db1, x2*db2));
    float kc    = sqrtf(fmaf(0.2f, fabsf(n), 1.0f));
    float gdb_r = fmaf(og0,db0, fmaf(og1,db1, og2*db2));
    float gdb_i = fmaf(og3,db0, fmaf(og4,db1, og5*db2));
    float gx_r  = fmaf(og0,x0,  fmaf(og1,x1,  og2*x2));
    float gx_i  = fmaf(og3,x0,  fmaf(og4,x1,  og5*x2));
    float gb_r  = kc * fmaf(gamma*xdb, gx_r, 0.5f*gdb_r);
    float gb_i  = kc * fmaf(gamma*xdb, gx_i, 0.5f*gdb_i);

    float alpha = 0.5f*(n + 1.0f);
    float beta  = fmaf(0.4f, fabsf(n), 0.1f);
    float cf    = 0.1f*(1.0f + t)*DTf;
    float sr = gb_r - (alpha*dup0 + beta*dum0)*DTf - cf*(og0+og1+og2);
    float si = gb_i - (alpha*dup1 + beta*dum1)*DTf - cf*(og3+og4+og5);

    float sp, cp;
    __sincosf(phi, &sp, &cp);
    if (act)
        dA[idx] = make_float2(fmaf(cp, sr,  sp*si), fmaf(cp, si, -sp*sr));
}

// ---- Pass 2b: JUMP tasks only (single-sided; no grad, no dB/t loads) ----
__global__ void __launch_bounds__(256) k_step_jump(
    const float* __restrict__ N,  const float* __restrict__ X,
    const float* __restrict__ P,
    const float* __restrict__ Wj1, const float* __restrict__ bj1,
    const float* __restrict__ Wj2,
    const float* __restrict__ phiA,
    const unsigned short* __restrict__ jumpList, const int2* __restrict__ counters,
    float2* __restrict__ dA)
{
    int k = blockIdx.y;
    int count = counters[k].y;
    int start = blockIdx.x*256;
    if (start >= count) return;

    const float* v1  = Wj1 + k*5*HID;
    const float* c1  = bj1 + k*HID;
    const float* vw2 = Wj2 + k*HID*2;

    __shared__ float Td[HID];
    if (threadIdx.x < HID) Td[threadIdx.x] = fast_tanh(v1[threadIdx.x]);
    __syncthreads();

    int slot = start + threadIdx.x;
    bool act = slot < count;
    unsigned short ent = jumpList[(size_t)k*BATCH + (act ? slot : count - 1)];
    float sgn = (ent & 0x8000) ? -1.0f : 1.0f;
    int   ob  = ent & 0x7FFF;
    size_t idx = (size_t)k*BATCH + ob;
    float n = N[idx], p = P[idx];
    const float* xp = X + idx*3;
    float x0 = xp[0], x1 = xp[1], x2 = xp[2];
    float phi = phiA[idx];

    float sr, si;
    jump_mlp_1s(n,x0,x1,x2,p, sgn, v1,c1,vw2,Td, sr, si);

    float sp, cp;
    __sincosf(phi, &sp, &cp);
    if (act)
        dA[idx] = make_float2(fmaf(cp, sr,  sp*si), fmaf(cp, si, -sp*sr));
}

// ---- Pass 3: u0 MLP + affine fold (c recomputed from N/P) + g ----
__global__ void __launch_bounds__(256) k_combine(
    const float* __restrict__ N, const float* __restrict__ X, const float* __restrict__ P,
    const float* __restrict__ Wr1, const float* __restrict__ br1,
    const float* __restrict__ Wr2, const float* __restrict__ br2,
    const float2* __restrict__ dA,
    const float* __restrict__ phiF, float* __restrict__ out, int full)
{
    int b = blockIdx.x*256 + threadIdx.x;
    const float* xp = X + (size_t)b*3;
    float ur, ui;
    mlp_u0(N[b], xp[0], xp[1], xp[2], P[b], Wr1, br1, Wr2, br2, ur, ui);
    float nprev = N[b];
#pragma unroll 4
    for (int k = 0; k < NSTEPS; k++) {
        size_t idx = (size_t)k*BATCH + b;
        float nnext = N[idx + BATCH];
        float c = (nnext == nprev) ? (1.0f - P[idx]*DTf) : 1.0f;
        float2 d = dA[idx];
        ur = fmaf(c, ur, d.x);
        ui = fmaf(c, ui, d.y);
        nprev = nnext;
    }
    float phi = phiF[b];
    const float* xf = X + ((size_t)NSTEPS*BATCH + b)*3;
    float s = xf[0] + xf[1] + xf[2];
    float sp, cp;
    __sincosf(phi, &sp, &cp);
    float gre =  s*cp;
    float gim = -s*sp;
    if (full) {
        out[b]           = ur;
        out[BATCH + b]   = ui;
        out[2*BATCH + b] = gre;
        out[3*BATCH + b] = gim;
    } else {
        out[b]         = ur;
        out[BATCH + b] = gre;
    }
}

// ---- Fallback (no workspace) ----
__global__ void __launch_bounds__(256) k_fused(
    const float* __restrict__ N,  const float* __restrict__ X,
    const float* __restrict__ P,  const float* __restrict__ Tarr,
    const float* __restrict__ dB,
    const float* __restrict__ Wr1, const float* __restrict__ br1,
    const float* __restrict__ Wr2, const float* __restrict__ br2,
    const float* __restrict__ Wg1, const float* __restrict__ bg1,
    const float* __restrict__ Wg2, const float* __restrict__ bg2,
    const float* __restrict__ Wj1, const float* __restrict__ bj1,
    const float* __restrict__ Wj2, const float* __restrict__ bj2,
    float* __restrict__ out, int full)
{
    int b = blockIdx.x*256 + threadIdx.x;
    float ur, ui;
    {
        const float* xp = X + (size_t)b*3;
        mlp_u0(N[b], xp[0], xp[1], xp[2], P[b], Wr1, br1, Wr2, br2, ur, ui);
    }
    double s = 0.0;
    for (int k = 0; k < NSTEPS; k++) {
        size_t idx = (size_t)k*BATCH + b;
        float n = N[idx], p = P[idx], t = Tarr[k];
        const float* xp  = X  + idx*3;
        const float* dbp = dB + idx*3;
        float dN  = N[idx + BATCH] - n;
        float phi = (float)(DTf * s);
        CD cd = step_core<false>(n, xp[0], xp[1], xp[2], p, t,
                                 dbp[0], dbp[1], dbp[2], dN, phi,
                                 Wg1 + k*5*HID, bg1 + k*HID,
                                 Wg2 + k*HID*6, bg2 + k*6,
                                 Wj1 + k*5*HID, bj1 + k*HID,
                                 Wj2 + k*HID*2, nullptr);
        ur = fmaf(cd.c, ur, cd.dre);
        ui = fmaf(cd.c, ui, cd.dim);
        float x0 = xp[0], x1 = xp[1], x2 = xp[2];
        s += (double)p * (double)(x0*x0 + x1*x1 + x2*x2);
    }
    float phi = (float)(DTf * s);
    const float* xf = X + ((size_t)NSTEPS*BATCH + b)*3;
    float sm = xf[0] + xf[1] + xf[2];
    float sp, cp;
    __sincosf(phi, &sp, &cp);
    float gre =  sm*cp;
    float gim = -sm*sp;
    if (full) {
        out[b]           = ur;
        out[BATCH + b]   = ui;
        out[2*BATCH + b] = gre;
        out[3*BATCH + b] = gim;
    } else {
        out[b]         = ur;
        out[BATCH + b] = gre;
    }
}

extern "C" void kernel_launch(void* const* d_in, const int* in_sizes, int n_in,
                              void* d_out, int out_size, void* d_ws, size_t ws_size,
                              hipStream_t stream)
{
    const float* N    = (const float*)d_in[0];
    const float* X    = (const float*)d_in[1];
    const float* P    = (const float*)d_in[2];
    const float* Tarr = (const float*)d_in[3];
    const float* dB   = (const float*)d_in[4];
    const float* Wr1  = (const float*)d_in[5];
    const float* br1  = (const float*)d_in[6];
    const float* Wr2  = (const float*)d_in[7];
    const float* br2  = (const float*)d_in[8];
    const float* Wg1  = (const float*)d_in[9];
    const float* bg1  = (const float*)d_in[10];
    const float* Wg2  = (const float*)d_in[11];
    const float* bg2  = (const float*)d_in[12];
    const float* Wj1  = (const float*)d_in[13];
    const float* bj1  = (const float*)d_in[14];
    const float* Wj2  = (const float*)d_in[15];
    const float* bj2  = (const float*)d_in[16];
    float* out = (float*)d_out;

    const int full = (out_size >= 4*BATCH) ? 1 : 0;

    const size_t phi_elems = (size_t)NSTEPS*BATCH;
    // layout: phiA (f32) | phiF (f32) | dA (float2) | fullList (u16) |
    //         jumpList (u16) | counters (int2[NSTEPS])
    const size_t off_phiF = phi_elems*4;
    const size_t off_dA   = off_phiF + (size_t)BATCH*4;
    const size_t off_fl   = off_dA + phi_elems*8;
    const size_t off_jl   = off_fl + phi_elems*2;
    const size_t off_cnt  = off_jl + phi_elems*2;
    const size_t need     = off_cnt + NSTEPS*sizeof(int2);

    if (ws_size >= need) {
        char* ws = (char*)d_ws;
        float*          phiA = (float*)ws;
        float*          phiF = (float*)(ws + off_phiF);
        float2*         dA   = (float2*)(ws + off_dA);
        unsigned short* fL   = (unsigned short*)(ws + off_fl);
        unsigned short* jL   = (unsigned short*)(ws + off_jl);
        int2*           cnts = (int2*)(ws + off_cnt);

        hipMemsetAsync(cnts, 0, NSTEPS*sizeof(int2), stream);
        k_phi<<<dim3(BATCH/256), dim3(256), 0, stream>>>(X, P, phiA, phiF);
        k_classify<<<dim3(BATCH/256, NSTEPS), dim3(256), 0, stream>>>(N, fL, jL, cnts);
        k_step_full<<<dim3(BATCH/256, NSTEPS), dim3(256), 0, stream>>>(
            N, X, P, Tarr, dB, Wg1, bg1, Wg2, bg2, Wj1, bj1, Wj2, bj2,
            phiA, fL, cnts, dA);
        k_step_jump<<<dim3(BATCH/256, NSTEPS), dim3(256), 0, stream>>>(
            N, X, P, Wj1, bj1, Wj2, phiA, jL, cnts, dA);
        k_combine<<<dim3(BATCH/256), dim3(256), 0, stream>>>(
            N, X, P, Wr1, br1, Wr2, br2, dA, phiF, out, full);
    } else {
        k_fused<<<dim3(BATCH/256), dim3(256), 0, stream>>>(
            N, X, P, Tarr, dB, Wr1, br1, Wr2, br2,
            Wg1, bg1, Wg2, bg2, Wj1, bj1, Wj2, bj2, out, full);
    }
}

// Round 17
// 282.601 us; speedup vs baseline: 1.6384x; 1.6384x over previous
//
#include <hip/hip_runtime.h>
#include <math.h>

#define NSTEPS 128
#define BATCH  32768
#define HID    64
#define TPT    4            // tasks per thread (ILP)
#define BLKT   256          // threads per block
#define WIN    (BLKT*TPT)   // tasks per block window = 1024

constexpr float DTf = 1.0f / 128.0f;
constexpr float TWO_LOG2E = 2.88539008177792681f;

typedef float v2f __attribute__((ext_vector_type(2)));

__device__ __forceinline__ v2f v2ld(const float* p) { return *(const v2f*)p; }
__device__ __forceinline__ v2f bc(float s) { v2f r = {s, s}; return r; }
__device__ __forceinline__ v2f pkfma(v2f a, v2f b, v2f c) {
    return __builtin_elementwise_fma(a, b, c);
}

struct CD { float c, dre, dim; };

__device__ __forceinline__ float fast_tanh(float x) {
    float e = __builtin_amdgcn_exp2f(x * TWO_LOG2E);
    return 1.0f - 2.0f * __builtin_amdgcn_rcpf(e + 1.0f);
}
__device__ __forceinline__ v2f fast_tanh2(v2f z) {
    v2f zs = z * TWO_LOG2E;
    v2f e;
    e.x = __builtin_amdgcn_exp2f(zs.x);
    e.y = __builtin_amdgcn_exp2f(zs.y);
    v2f e1 = e + 1.0f;
    v2f r;
    r.x = __builtin_amdgcn_rcpf(e1.x);
    r.y = __builtin_amdgcn_rcpf(e1.y);
    return pkfma(bc(-2.0f), r, bc(1.0f));
}

// ---------- single-task versions (fallback path) ----------
__device__ __forceinline__ void grad_mlp(
    float n, float x0, float x1, float x2, float p,
    const float* __restrict__ w1, const float* __restrict__ b1,
    const float* __restrict__ w2, const float* __restrict__ b2,
    float& og0, float& og1, float& og2, float& og3, float& og4, float& og5)
{
    v2f og01 = { b2[0], b2[1] };
    v2f og23 = { b2[2], b2[3] };
    v2f og45 = { b2[4], b2[5] };
#pragma unroll 4
    for (int j = 0; j < HID; j += 2) {
        v2f z = pkfma(bc(n),  v2ld(w1 + j),
                pkfma(bc(x0), v2ld(w1 + HID   + j),
                pkfma(bc(x1), v2ld(w1 + 2*HID + j),
                pkfma(bc(x2), v2ld(w1 + 3*HID + j),
                pkfma(bc(p),  v2ld(w1 + 4*HID + j), v2ld(b1 + j))))));
        v2f h = fast_tanh2(z);
        const float* wj = w2 + j*6;
        og01 = pkfma(bc(h.x), v2ld(wj),     pkfma(bc(h.y), v2ld(wj + 6),  og01));
        og23 = pkfma(bc(h.x), v2ld(wj + 2), pkfma(bc(h.y), v2ld(wj + 8),  og23));
        og45 = pkfma(bc(h.x), v2ld(wj + 4), pkfma(bc(h.y), v2ld(wj + 10), og45));
    }
    og0 = og01.x; og1 = og01.y; og2 = og23.x;
    og3 = og23.y; og4 = og45.x; og5 = og45.y;
}

template<bool USE_TD>
__device__ __forceinline__ void jump_mlp(
    float n, float x0, float x1, float x2, float p,
    const float* __restrict__ v1, const float* __restrict__ c1,
    const float* __restrict__ vw2, const float* __restrict__ Td,
    float& dup0, float& dup1, float& dum0, float& dum1)
{
    v2f dup01 = { 0.f, 0.f };
    v2f dum01 = { 0.f, 0.f };
#pragma unroll 4
    for (int j = 0; j < HID; j += 2) {
        v2f d  = v2ld(v1 + j);
        v2f zb = pkfma(bc(n), d,
                 pkfma(bc(x0), v2ld(v1 + HID   + j),
                 pkfma(bc(x1), v2ld(v1 + 2*HID + j),
                 pkfma(bc(x2), v2ld(v1 + 3*HID + j),
                 pkfma(bc(p),  v2ld(v1 + 4*HID + j), v2ld(c1 + j))))));
        v2f T  = fast_tanh2(zb);
        v2f Tv;
        if (USE_TD) Tv = v2ld(Td + j);
        else { Tv.x = fast_tanh(d.x); Tv.y = fast_tanh(d.y); }
        v2f a    = T * Tv;
        v2f oma2 = pkfma(-a, a, bc(1.0f));
        v2f r;
        r.x = __builtin_amdgcn_rcpf(oma2.x);
        r.y = __builtin_amdgcn_rcpf(oma2.y);
        v2f s1 = (T + Tv) * r;
        v2f u1 = s1 - T;
        v2f ep = pkfma(-s1, a, u1);
        v2f s2 = (T - Tv) * r;
        v2f u2 = s2 - T;
        v2f em = pkfma(s2, a, u2);
        v2f wv0 = v2ld(vw2 + 2*j);
        v2f wv1 = v2ld(vw2 + 2*j + 2);
        dup01 = pkfma(bc(ep.x), wv0, pkfma(bc(ep.y), wv1, dup01));
        dum01 = pkfma(bc(em.x), wv0, pkfma(bc(em.y), wv1, dum01));
    }
    dup0 = dup01.x; dup1 = dup01.y;
    dum0 = dum01.x; dum1 = dum01.y;
}

template<bool USE_TD>
__device__ __forceinline__ CD step_core(
    float n, float x0, float x1, float x2, float p, float t,
    float db0, float db1, float db2, float dN, float phi,
    const float* __restrict__ w1, const float* __restrict__ b1,
    const float* __restrict__ w2, const float* __restrict__ b2,
    const float* __restrict__ v1, const float* __restrict__ c1,
    const float* __restrict__ vw2, const float* __restrict__ Td)
{
    float og0, og1, og2, og3, og4, og5;
    grad_mlp(n,x0,x1,x2,p, w1,b1,w2,b2, og0,og1,og2,og3,og4,og5);
    float dup0, dup1, dum0, dum1;
    jump_mlp<USE_TD>(n,x0,x1,x2,p, v1,c1,vw2,Td, dup0,dup1,dum0,dum1);

    float r2    = fmaf(x0,x0, fmaf(x1,x1, x2*x2));
    float gamma = 0.1f - (0.5f + 0.1f*r2) * __builtin_amdgcn_rcpf(1.0f + r2);
    float xdb   = fmaf(x0,db0, fmaf(x1,db1, x2*db2));
    float kc    = sqrtf(fmaf(0.2f, fabsf(n), 1.0f));
    float gdb_r = fmaf(og0,db0, fmaf(og1,db1, og2*db2));
    float gdb_i = fmaf(og3,db0, fmaf(og4,db1, og5*db2));
    float gx_r  = fmaf(og0,x0,  fmaf(og1,x1,  og2*x2));
    float gx_i  = fmaf(og3,x0,  fmaf(og4,x1,  og5*x2));
    float gb_r  = kc * fmaf(gamma*xdb, gx_r, 0.5f*gdb_r);
    float gb_i  = kc * fmaf(gamma*xdb, gx_i, 0.5f*gdb_i);

    float alpha = 0.5f*(n + 1.0f);
    float beta  = fmaf(0.4f, fabsf(n), 0.1f);
    float cf    = 0.1f*(1.0f + t)*DTf;
    float d0r = gb_r - (alpha*dup0 + beta*dum0)*DTf - cf*(og0+og1+og2);
    float d0i = gb_i - (alpha*dup1 + beta*dum1)*DTf - cf*(og3+og4+og5);

    float c, sr, si;
    if (dN > 0.5f)       { c = 1.0f;          sr = dup0; si = dup1; }
    else if (dN < -0.5f) { c = 1.0f;          sr = dum0; si = dum1; }
    else                 { c = 1.0f - p*DTf;  sr = d0r;  si = d0i;  }

    float sp, cp;
    __sincosf(phi, &sp, &cp);
    CD o;
    o.c   = c;
    o.dre = fmaf(cp, sr,  sp*si);
    o.dim = fmaf(cp, si, -sp*sr);
    return o;
}

__device__ __forceinline__ void mlp_u0(
    float n, float x0, float x1, float x2, float p,
    const float* __restrict__ w1, const float* __restrict__ b1,
    const float* __restrict__ w2, const float* __restrict__ b2,
    float& ur, float& ui)
{
    v2f o01 = { b2[0], b2[1] };
#pragma unroll 4
    for (int j = 0; j < HID; j += 2) {
        v2f z = pkfma(bc(n),  v2ld(w1 + j),
                pkfma(bc(x0), v2ld(w1 + HID   + j),
                pkfma(bc(x1), v2ld(w1 + 2*HID + j),
                pkfma(bc(x2), v2ld(w1 + 3*HID + j),
                pkfma(bc(p),  v2ld(w1 + 4*HID + j), v2ld(b1 + j))))));
        v2f h = fast_tanh2(z);
        o01 = pkfma(bc(h.x), v2ld(w2 + 2*j), pkfma(bc(h.y), v2ld(w2 + 2*j + 2), o01));
    }
    ur = o01.x; ui = o01.y;
}

// ---- Pass 1: phi prefix ----
__global__ void __launch_bounds__(256) k_phi(
    const float* __restrict__ X, const float* __restrict__ P,
    float* __restrict__ phi, float* __restrict__ phiF)
{
    int b = blockIdx.x*256 + threadIdx.x;
    double s = 0.0;
    for (int k = 0; k < NSTEPS; k++) {
        size_t idx = (size_t)k*BATCH + b;
        phi[idx] = (float)(DTf * s);
        float p = P[idx];
        const float* xp = X + idx*3;
        float x0 = xp[0], x1 = xp[1], x2 = xp[2];
        s += (double)p * (double)(x0*x0 + x1*x1 + x2*x2);
    }
    phiF[b] = (float)(DTf * s);
}

// ---- Pass 2: in-block compaction + 4 tasks/thread (ILP + weight amortization) ----
// Each thread owns 4 compacted slots; weights are loaded once per j-iter and
// applied to 4 independent task chains. Atomic rank order nondeterministic but
// results are pure per-task functions written keyed by original index.
__global__ void __launch_bounds__(BLKT) k_step(
    const float* __restrict__ N,  const float* __restrict__ X,
    const float* __restrict__ P,  const float* __restrict__ Tarr,
    const float* __restrict__ dB,
    const float* __restrict__ Wg1, const float* __restrict__ bg1,
    const float* __restrict__ Wg2, const float* __restrict__ bg2,
    const float* __restrict__ Wj1, const float* __restrict__ bj1,
    const float* __restrict__ Wj2, const float* __restrict__ bj2,
    const float* __restrict__ phiA, float* __restrict__ cA, float2* __restrict__ dA)
{
    int k = blockIdx.y;
    const float* w1  = Wg1 + k*5*HID;
    const float* b1  = bg1 + k*HID;
    const float* w2  = Wg2 + k*HID*6;
    const float* b2  = bg2 + k*6;
    const float* v1  = Wj1 + k*5*HID;
    const float* c1  = bj1 + k*HID;
    const float* vw2 = Wj2 + k*HID*2;
    float t = Tarr[k];

    __shared__ float Td[HID];
    __shared__ unsigned short sorig[WIN];
    __shared__ int cnt[2];
    if (threadIdx.x < HID) Td[threadIdx.x] = fast_tanh(v1[threadIdx.x]);
    if (threadIdx.x == 0) { cnt[0] = 0; cnt[1] = 0; }
    __syncthreads();

    int tid  = threadIdx.x;
    int base = blockIdx.x*WIN;
#pragma unroll
    for (int u = 0; u < TPT; ++u) {
        int lb = tid + u*BLKT;                 // coalesced classify loads
        size_t i0 = (size_t)k*BATCH + base + lb;
        float dN0 = N[i0 + BATCH] - N[i0];     // exact +-1/0 in fp32
        bool f0 = (dN0 == 0.0f);
        int pos = f0 ? atomicAdd(&cnt[0], 1) : (WIN-1) - atomicAdd(&cnt[1], 1);
        sorig[pos] = (unsigned short)lb;
    }
    __syncthreads();

    int   ob[TPT];
    float n_[TPT], p_[TPT], x0_[TPT], x1_[TPT], x2_[TPT];
    float db0_[TPT], db1_[TPT], db2_[TPT], phi_[TPT], dN_[TPT];
    bool anyfull = false;
#pragma unroll
    for (int v = 0; v < TPT; ++v) {
        int lb = sorig[TPT*tid + v];
        ob[v] = base + lb;
        size_t idx = (size_t)k*BATCH + ob[v];
        n_[v] = N[idx]; p_[v] = P[idx];
        dN_[v] = N[idx + BATCH] - n_[v];
        const float* xp  = X  + idx*3;
        x0_[v]=xp[0]; x1_[v]=xp[1]; x2_[v]=xp[2];
        const float* dbp = dB + idx*3;
        db0_[v]=dbp[0]; db1_[v]=dbp[1]; db2_[v]=dbp[2];
        phi_[v] = phiA[idx];
        anyfull |= (dN_[v] == 0.0f);
    }

    float c_[TPT], sr_[TPT], si_[TPT];

    if (__ballot(anyfull) != 0ull) {
        // ======== full/mixed wave: 4-way grad + 4-way double-sided jump ========
        v2f og01[TPT], og23[TPT], og45[TPT];
#pragma unroll
        for (int v = 0; v < TPT; ++v) {
            og01[v] = (v2f){ b2[0], b2[1] };
            og23[v] = (v2f){ b2[2], b2[3] };
            og45[v] = (v2f){ b2[4], b2[5] };
        }
        for (int j = 0; j < HID; j += 2) {
            v2f g0=v2ld(w1+j), g1=v2ld(w1+HID+j), g2=v2ld(w1+2*HID+j),
                g3=v2ld(w1+3*HID+j), g4=v2ld(w1+4*HID+j), gb=v2ld(b1+j);
            const float* wj = w2 + j*6;
            v2f a0=v2ld(wj), a1=v2ld(wj+6), a2=v2ld(wj+2),
                a3=v2ld(wj+8), a4=v2ld(wj+4), a5=v2ld(wj+10);
#pragma unroll
            for (int v = 0; v < TPT; ++v) {
                v2f z = pkfma(bc(n_[v]), g0,
                        pkfma(bc(x0_[v]), g1,
                        pkfma(bc(x1_[v]), g2,
                        pkfma(bc(x2_[v]), g3,
                        pkfma(bc(p_[v]),  g4, gb)))));
                v2f h = fast_tanh2(z);
                og01[v] = pkfma(bc(h.x), a0, pkfma(bc(h.y), a1, og01[v]));
                og23[v] = pkfma(bc(h.x), a2, pkfma(bc(h.y), a3, og23[v]));
                og45[v] = pkfma(bc(h.x), a4, pkfma(bc(h.y), a5, og45[v]));
            }
        }
        v2f dup[TPT], dum[TPT];
#pragma unroll
        for (int v = 0; v < TPT; ++v) { dup[v] = (v2f){0.f,0.f}; dum[v] = (v2f){0.f,0.f}; }
        for (int j = 0; j < HID; j += 2) {
            v2f jd=v2ld(v1+j), j1=v2ld(v1+HID+j), j2=v2ld(v1+2*HID+j),
                j3=v2ld(v1+3*HID+j), j4=v2ld(v1+4*HID+j), jc=v2ld(c1+j);
            v2f tv = v2ld(Td + j);
            v2f wv0=v2ld(vw2+2*j), wv1=v2ld(vw2+2*j+2);
#pragma unroll
            for (int v = 0; v < TPT; ++v) {
                v2f zb = pkfma(bc(n_[v]), jd,
                         pkfma(bc(x0_[v]), j1,
                         pkfma(bc(x1_[v]), j2,
                         pkfma(bc(x2_[v]), j3,
                         pkfma(bc(p_[v]),  j4, jc)))));
                v2f T = fast_tanh2(zb);
                v2f a = T * tv;
                v2f om = pkfma(-a, a, bc(1.0f));
                v2f r;
                r.x = __builtin_amdgcn_rcpf(om.x);
                r.y = __builtin_amdgcn_rcpf(om.y);
                v2f s1 = (T + tv) * r;
                v2f u1 = s1 - T;
                v2f ep = pkfma(-s1, a, u1);
                v2f s2 = (T - tv) * r;
                v2f u2 = s2 - T;
                v2f em = pkfma(s2, a, u2);
                dup[v] = pkfma(bc(ep.x), wv0, pkfma(bc(ep.y), wv1, dup[v]));
                dum[v] = pkfma(bc(em.x), wv0, pkfma(bc(em.y), wv1, dum[v]));
            }
        }
#pragma unroll
        for (int v = 0; v < TPT; ++v) {
            float og0=og01[v].x, og1=og01[v].y, og2=og23[v].x;
            float og3=og23[v].y, og4=og45[v].x, og5=og45[v].y;
            float x0=x0_[v], x1=x1_[v], x2=x2_[v];
            float n=n_[v], p=p_[v];
            float r2    = fmaf(x0,x0, fmaf(x1,x1, x2*x2));
            float gamma = 0.1f - (0.5f + 0.1f*r2) * __builtin_amdgcn_rcpf(1.0f + r2);
            float xdb   = fmaf(x0,db0_[v], fmaf(x1,db1_[v], x2*db2_[v]));
            float kc    = sqrtf(fmaf(0.2f, fabsf(n), 1.0f));
            float gdb_r = fmaf(og0,db0_[v], fmaf(og1,db1_[v], og2*db2_[v]));
            float gdb_i = fmaf(og3,db0_[v], fmaf(og4,db1_[v], og5*db2_[v]));
            float gx_r  = fmaf(og0,x0,  fmaf(og1,x1,  og2*x2));
            float gx_i  = fmaf(og3,x0,  fmaf(og4,x1,  og5*x2));
            float gb_r  = kc * fmaf(gamma*xdb, gx_r, 0.5f*gdb_r);
            float gb_i  = kc * fmaf(gamma*xdb, gx_i, 0.5f*gdb_i);
            float alpha = 0.5f*(n + 1.0f);
            float beta  = fmaf(0.4f, fabsf(n), 0.1f);
            float cf    = 0.1f*(1.0f + t)*DTf;
            float d0r = gb_r - (alpha*dup[v].x + beta*dum[v].x)*DTf - cf*(og0+og1+og2);
            float d0i = gb_i - (alpha*dup[v].y + beta*dum[v].y)*DTf - cf*(og3+og4+og5);
            if (dN_[v] > 0.5f)       { c_[v]=1.0f;             sr_[v]=dup[v].x; si_[v]=dup[v].y; }
            else if (dN_[v] < -0.5f) { c_[v]=1.0f;             sr_[v]=dum[v].x; si_[v]=dum[v].y; }
            else                     { c_[v]=1.0f - p*DTf;     sr_[v]=d0r;      si_[v]=d0i;      }
        }
    } else {
        // ======== pure jump wave: 4-way single-sided ========
        v2f acc[TPT];
        float sgn[TPT];
#pragma unroll
        for (int v = 0; v < TPT; ++v) { acc[v] = (v2f){0.f,0.f}; sgn[v] = dN_[v]; }
        for (int j = 0; j < HID; j += 2) {
            v2f jd=v2ld(v1+j), j1=v2ld(v1+HID+j), j2=v2ld(v1+2*HID+j),
                j3=v2ld(v1+3*HID+j), j4=v2ld(v1+4*HID+j), jc=v2ld(c1+j);
            v2f tv = v2ld(Td + j);
            v2f wv0=v2ld(vw2+2*j), wv1=v2ld(vw2+2*j+2);
#pragma unroll
            for (int v = 0; v < TPT; ++v) {
                v2f zb = pkfma(bc(n_[v]), jd,
                         pkfma(bc(x0_[v]), j1,
                         pkfma(bc(x1_[v]), j2,
                         pkfma(bc(x2_[v]), j3,
                         pkfma(bc(p_[v]),  j4, jc)))));
                v2f T   = fast_tanh2(zb);
                v2f Tsv = bc(sgn[v]) * tv;       // tanh(sgn*d) = sgn*tanh(d)
                v2f as  = T * Tsv;
                v2f om  = pkfma(-as, as, bc(1.0f));
                v2f r;
                r.x = __builtin_amdgcn_rcpf(om.x);
                r.y = __builtin_amdgcn_rcpf(om.y);
                v2f s1 = (T + Tsv) * r;
                v2f u1 = s1 - T;
                v2f e  = pkfma(-s1, as, u1);
                acc[v] = pkfma(bc(e.x), wv0, pkfma(bc(e.y), wv1, acc[v]));
            }
        }
#pragma unroll
        for (int v = 0; v < TPT; ++v) {
            c_[v] = 1.0f; sr_[v] = acc[v].x; si_[v] = acc[v].y;
        }
    }

#pragma unroll
    for (int v = 0; v < TPT; ++v) {
        float sp, cp;
        __sincosf(phi_[v], &sp, &cp);
        size_t oidx = (size_t)k*BATCH + ob[v];
        cA[oidx] = c_[v];
        dA[oidx] = make_float2(fmaf(cp, sr_[v],  sp*si_[v]),
                               fmaf(cp, si_[v], -sp*sr_[v]));
    }
}

// ---- Pass 3: u0 MLP + affine fold + g ----
__global__ void __launch_bounds__(256) k_combine(
    const float* __restrict__ N, const float* __restrict__ X, const float* __restrict__ P,
    const float* __restrict__ Wr1, const float* __restrict__ br1,
    const float* __restrict__ Wr2, const float* __restrict__ br2,
    const float* __restrict__ cA, const float2* __restrict__ dA,
    const float* __restrict__ phiF, float* __restrict__ out, int full)
{
    int b = blockIdx.x*256 + threadIdx.x;
    const float* xp = X + (size_t)b*3;
    float ur, ui;
    mlp_u0(N[b], xp[0], xp[1], xp[2], P[b], Wr1, br1, Wr2, br2, ur, ui);
#pragma unroll 8
    for (int k = 0; k < NSTEPS; k++) {
        size_t idx = (size_t)k*BATCH + b;
        float  c = cA[idx];
        float2 d = dA[idx];
        ur = fmaf(c, ur, d.x);
        ui = fmaf(c, ui, d.y);
    }
    float phi = phiF[b];
    const float* xf = X + ((size_t)NSTEPS*BATCH + b)*3;
    float s = xf[0] + xf[1] + xf[2];
    float sp, cp;
    __sincosf(phi, &sp, &cp);
    float gre =  s*cp;
    float gim = -s*sp;
    if (full) {
        out[b]           = ur;
        out[BATCH + b]   = ui;
        out[2*BATCH + b] = gre;
        out[3*BATCH + b] = gim;
    } else {
        out[b]         = ur;
        out[BATCH + b] = gre;
    }
}

// ---- Fallback (no workspace) ----
__global__ void __launch_bounds__(256) k_fused(
    const float* __restrict__ N,  const float* __restrict__ X,
    const float* __restrict__ P,  const float* __restrict__ Tarr,
    const float* __restrict__ dB,
    const float* __restrict__ Wr1, const float* __restrict__ br1,
    const float* __restrict__ Wr2, const float* __restrict__ br2,
    const float* __restrict__ Wg1, const float* __restrict__ bg1,
    const float* __restrict__ Wg2, const float* __restrict__ bg2,
    const float* __restrict__ Wj1, const float* __restrict__ bj1,
    const float* __restrict__ Wj2, const float* __restrict__ bj2,
    float* __restrict__ out, int full)
{
    int b = blockIdx.x*256 + threadIdx.x;
    float ur, ui;
    {
        const float* xp = X + (size_t)b*3;
        mlp_u0(N[b], xp[0], xp[1], xp[2], P[b], Wr1, br1, Wr2, br2, ur, ui);
    }
    double s = 0.0;
    for (int k = 0; k < NSTEPS; k++) {
        size_t idx = (size_t)k*BATCH + b;
        float n = N[idx], p = P[idx], t = Tarr[k];
        const float* xp  = X  + idx*3;
        const float* dbp = dB + idx*3;
        float dN  = N[idx + BATCH] - n;
        float phi = (float)(DTf * s);
        CD cd = step_core<false>(n, xp[0], xp[1], xp[2], p, t,
                                 dbp[0], dbp[1], dbp[2], dN, phi,
                                 Wg1 + k*5*HID, bg1 + k*HID,
                                 Wg2 + k*HID*6, bg2 + k*6,
                                 Wj1 + k*5*HID, bj1 + k*HID,
                                 Wj2 + k*HID*2, nullptr);
        ur = fmaf(cd.c, ur, cd.dre);
        ui = fmaf(cd.c, ui, cd.dim);
        float x0 = xp[0], x1 = xp[1], x2 = xp[2];
        s += (double)p * (double)(x0*x0 + x1*x1 + x2*x2);
    }
    float phi = (float)(DTf * s);
    const float* xf = X + ((size_t)NSTEPS*BATCH + b)*3;
    float sm = xf[0] + xf[1] + xf[2];
    float sp, cp;
    __sincosf(phi, &sp, &cp);
    float gre =  sm*cp;
    float gim = -sm*sp;
    if (full) {
        out[b]           = ur;
        out[BATCH + b]   = ui;
        out[2*BATCH + b] = gre;
        out[3*BATCH + b] = gim;
    } else {
        out[b]         = ur;
        out[BATCH + b] = gre;
    }
}

extern "C" void kernel_launch(void* const* d_in, const int* in_sizes, int n_in,
                              void* d_out, int out_size, void* d_ws, size_t ws_size,
                              hipStream_t stream)
{
    const float* N    = (const float*)d_in[0];
    const float* X    = (const float*)d_in[1];
    const float* P    = (const float*)d_in[2];
    const float* Tarr = (const float*)d_in[3];
    const float* dB   = (const float*)d_in[4];
    const float* Wr1  = (const float*)d_in[5];
    const float* br1  = (const float*)d_in[6];
    const float* Wr2  = (const float*)d_in[7];
    const float* br2  = (const float*)d_in[8];
    const float* Wg1  = (const float*)d_in[9];
    const float* bg1  = (const float*)d_in[10];
    const float* Wg2  = (const float*)d_in[11];
    const float* bg2  = (const float*)d_in[12];
    const float* Wj1  = (const float*)d_in[13];
    const float* bj1  = (const float*)d_in[14];
    const float* Wj2  = (const float*)d_in[15];
    const float* bj2  = (const float*)d_in[16];
    float* out = (float*)d_out;

    const int full = (out_size >= 4*BATCH) ? 1 : 0;

    const size_t phi_elems = (size_t)NSTEPS*BATCH;
    const size_t need = (phi_elems + BATCH + phi_elems)*sizeof(float)
                      + phi_elems*sizeof(float2);

    if (ws_size >= need) {
        float*  phiA = (float*)d_ws;
        float*  phiF = phiA + phi_elems;
        float*  cA   = phiF + BATCH;
        float2* dA   = (float2*)(cA + phi_elems);

        k_phi<<<dim3(BATCH/256), dim3(256), 0, stream>>>(X, P, phiA, phiF);
        k_step<<<dim3(BATCH/WIN, NSTEPS), dim3(BLKT), 0, stream>>>(
            N, X, P, Tarr, dB, Wg1, bg1, Wg2, bg2, Wj1, bj1, Wj2, bj2,
            phiA, cA, dA);
        k_combine<<<dim3(BATCH/256), dim3(256), 0, stream>>>(
            N, X, P, Wr1, br1, Wr2, br2, cA, dA, phiF, out, full);
    } else {
        k_fused<<<dim3(BATCH/256), dim3(256), 0, stream>>>(
            N, X, P, Tarr, dB, Wr1, br1, Wr2, br2,
            Wg1, bg1, Wg2, bg2, Wj1, bj1, Wj2, bj2, out, full);
    }
}

// Round 18
// 215.467 us; speedup vs baseline: 2.1489x; 1.3116x over previous
//
#include <hip/hip_runtime.h>
#include <math.h>

#define NSTEPS 128
#define BATCH  32768
#define HID    64
#define BLKT   256           // threads per block
#define WIN    2048          // tasks per block window (8 passes of 256)
#define PASSES (WIN/BLKT)

constexpr float DTf = 1.0f / 128.0f;
constexpr float TWO_LOG2E = 2.88539008177792681f;

typedef float v2f __attribute__((ext_vector_type(2)));

__device__ __forceinline__ v2f v2ld(const float* p) { return *(const v2f*)p; }
__device__ __forceinline__ v2f bc(float s) { v2f r = {s, s}; return r; }
__device__ __forceinline__ v2f pkfma(v2f a, v2f b, v2f c) {
    return __builtin_elementwise_fma(a, b, c);
}

struct CD { float c, dre, dim; };

__device__ __forceinline__ float fast_tanh(float x) {
    float e = __builtin_amdgcn_exp2f(x * TWO_LOG2E);
    return 1.0f - 2.0f * __builtin_amdgcn_rcpf(e + 1.0f);
}
__device__ __forceinline__ v2f fast_tanh2(v2f z) {
    v2f zs = z * TWO_LOG2E;
    v2f e;
    e.x = __builtin_amdgcn_exp2f(zs.x);
    e.y = __builtin_amdgcn_exp2f(zs.y);
    v2f e1 = e + 1.0f;
    v2f r;
    r.x = __builtin_amdgcn_rcpf(e1.x);
    r.y = __builtin_amdgcn_rcpf(e1.y);
    return pkfma(bc(-2.0f), r, bc(1.0f));
}

// ---- grad MLP: 5 -> 64 -> 6, packed pairs ----
__device__ __forceinline__ void grad_mlp(
    float n, float x0, float x1, float x2, float p,
    const float* __restrict__ w1, const float* __restrict__ b1,
    const float* __restrict__ w2, const float* __restrict__ b2,
    float& og0, float& og1, float& og2, float& og3, float& og4, float& og5)
{
    v2f og01 = { b2[0], b2[1] };
    v2f og23 = { b2[2], b2[3] };
    v2f og45 = { b2[4], b2[5] };
#pragma unroll 4
    for (int j = 0; j < HID; j += 2) {
        v2f z = pkfma(bc(n),  v2ld(w1 + j),
                pkfma(bc(x0), v2ld(w1 + HID   + j),
                pkfma(bc(x1), v2ld(w1 + 2*HID + j),
                pkfma(bc(x2), v2ld(w1 + 3*HID + j),
                pkfma(bc(p),  v2ld(w1 + 4*HID + j), v2ld(b1 + j))))));
        v2f h = fast_tanh2(z);
        const float* wj = w2 + j*6;
        og01 = pkfma(bc(h.x), v2ld(wj),     pkfma(bc(h.y), v2ld(wj + 6),  og01));
        og23 = pkfma(bc(h.x), v2ld(wj + 2), pkfma(bc(h.y), v2ld(wj + 8),  og23));
        og45 = pkfma(bc(h.x), v2ld(wj + 4), pkfma(bc(h.y), v2ld(wj + 10), og45));
    }
    og0 = og01.x; og1 = og01.y; og2 = og23.x;
    og3 = og23.y; og4 = og45.x; og5 = og45.y;
}

// ---- jump MLP, double-sided ----
template<bool USE_TD>
__device__ __forceinline__ void jump_mlp(
    float n, float x0, float x1, float x2, float p,
    const float* __restrict__ v1, const float* __restrict__ c1,
    const float* __restrict__ vw2, const float* __restrict__ Td,
    float& dup0, float& dup1, float& dum0, float& dum1)
{
    v2f dup01 = { 0.f, 0.f };
    v2f dum01 = { 0.f, 0.f };
#pragma unroll 4
    for (int j = 0; j < HID; j += 2) {
        v2f d  = v2ld(v1 + j);
        v2f zb = pkfma(bc(n), d,
                 pkfma(bc(x0), v2ld(v1 + HID   + j),
                 pkfma(bc(x1), v2ld(v1 + 2*HID + j),
                 pkfma(bc(x2), v2ld(v1 + 3*HID + j),
                 pkfma(bc(p),  v2ld(v1 + 4*HID + j), v2ld(c1 + j))))));
        v2f T  = fast_tanh2(zb);
        v2f Tv;
        if (USE_TD) Tv = v2ld(Td + j);
        else { Tv.x = fast_tanh(d.x); Tv.y = fast_tanh(d.y); }
        v2f a    = T * Tv;
        v2f oma2 = pkfma(-a, a, bc(1.0f));
        v2f r;
        r.x = __builtin_amdgcn_rcpf(oma2.x);
        r.y = __builtin_amdgcn_rcpf(oma2.y);
        v2f s1 = (T + Tv) * r;
        v2f u1 = s1 - T;
        v2f ep = pkfma(-s1, a, u1);
        v2f s2 = (T - Tv) * r;
        v2f u2 = s2 - T;
        v2f em = pkfma(s2, a, u2);
        v2f wv0 = v2ld(vw2 + 2*j);
        v2f wv1 = v2ld(vw2 + 2*j + 2);
        dup01 = pkfma(bc(ep.x), wv0, pkfma(bc(ep.y), wv1, dup01));
        dum01 = pkfma(bc(em.x), wv0, pkfma(bc(em.y), wv1, dum01));
    }
    dup0 = dup01.x; dup1 = dup01.y;
    dum0 = dum01.x; dum1 = dum01.y;
}

// ---- jump MLP, single-sided (bit-identical to the matching double-sided arm) ----
__device__ __forceinline__ void jump_mlp_1s(
    float n, float x0, float x1, float x2, float p, float sgn,
    const float* __restrict__ v1, const float* __restrict__ c1,
    const float* __restrict__ vw2, const float* __restrict__ Td,
    float& e0, float& e1)
{
    v2f acc = { 0.f, 0.f };
#pragma unroll 4
    for (int j = 0; j < HID; j += 2) {
        v2f d  = v2ld(v1 + j);
        v2f zb = pkfma(bc(n), d,
                 pkfma(bc(x0), v2ld(v1 + HID   + j),
                 pkfma(bc(x1), v2ld(v1 + 2*HID + j),
                 pkfma(bc(x2), v2ld(v1 + 3*HID + j),
                 pkfma(bc(p),  v2ld(v1 + 4*HID + j), v2ld(c1 + j))))));
        v2f T   = fast_tanh2(zb);
        v2f Tsv = bc(sgn) * v2ld(Td + j);
        v2f as  = T * Tsv;
        v2f oma = pkfma(-as, as, bc(1.0f));
        v2f r;
        r.x = __builtin_amdgcn_rcpf(oma.x);
        r.y = __builtin_amdgcn_rcpf(oma.y);
        v2f s1 = (T + Tsv) * r;
        v2f u1 = s1 - T;
        v2f e  = pkfma(-s1, as, u1);
        acc = pkfma(bc(e.x), v2ld(vw2 + 2*j), pkfma(bc(e.y), v2ld(vw2 + 2*j + 2), acc));
    }
    e0 = acc.x; e1 = acc.y;
}

template<bool USE_TD>
__device__ __forceinline__ CD step_core(
    float n, float x0, float x1, float x2, float p, float t,
    float db0, float db1, float db2, float dN, float phi,
    const float* __restrict__ w1, const float* __restrict__ b1,
    const float* __restrict__ w2, const float* __restrict__ b2,
    const float* __restrict__ v1, const float* __restrict__ c1,
    const float* __restrict__ vw2, const float* __restrict__ Td)
{
    float og0, og1, og2, og3, og4, og5;
    grad_mlp(n,x0,x1,x2,p, w1,b1,w2,b2, og0,og1,og2,og3,og4,og5);
    float dup0, dup1, dum0, dum1;
    jump_mlp<USE_TD>(n,x0,x1,x2,p, v1,c1,vw2,Td, dup0,dup1,dum0,dum1);

    float r2    = fmaf(x0,x0, fmaf(x1,x1, x2*x2));
    float gamma = 0.1f - (0.5f + 0.1f*r2) * __builtin_amdgcn_rcpf(1.0f + r2);
    float xdb   = fmaf(x0,db0, fmaf(x1,db1, x2*db2));
    float kc    = sqrtf(fmaf(0.2f, fabsf(n), 1.0f));
    float gdb_r = fmaf(og0,db0, fmaf(og1,db1, og2*db2));
    float gdb_i = fmaf(og3,db0, fmaf(og4,db1, og5*db2));
    float gx_r  = fmaf(og0,x0,  fmaf(og1,x1,  og2*x2));
    float gx_i  = fmaf(og3,x0,  fmaf(og4,x1,  og5*x2));
    float gb_r  = kc * fmaf(gamma*xdb, gx_r, 0.5f*gdb_r);
    float gb_i  = kc * fmaf(gamma*xdb, gx_i, 0.5f*gdb_i);

    float alpha = 0.5f*(n + 1.0f);
    float beta  = fmaf(0.4f, fabsf(n), 0.1f);
    float cf    = 0.1f*(1.0f + t)*DTf;
    float d0r = gb_r - (alpha*dup0 + beta*dum0)*DTf - cf*(og0+og1+og2);
    float d0i = gb_i - (alpha*dup1 + beta*dum1)*DTf - cf*(og3+og4+og5);

    float c, sr, si;
    if (dN > 0.5f)       { c = 1.0f;          sr = dup0; si = dup1; }
    else if (dN < -0.5f) { c = 1.0f;          sr = dum0; si = dum1; }
    else                 { c = 1.0f - p*DTf;  sr = d0r;  si = d0i;  }

    float sp, cp;
    __sincosf(phi, &sp, &cp);
    CD o;
    o.c   = c;
    o.dre = fmaf(cp, sr,  sp*si);
    o.dim = fmaf(cp, si, -sp*sr);
    return o;
}

__device__ __forceinline__ void mlp_u0(
    float n, float x0, float x1, float x2, float p,
    const float* __restrict__ w1, const float* __restrict__ b1,
    const float* __restrict__ w2, const float* __restrict__ b2,
    float& ur, float& ui)
{
    v2f o01 = { b2[0], b2[1] };
#pragma unroll 4
    for (int j = 0; j < HID; j += 2) {
        v2f z = pkfma(bc(n),  v2ld(w1 + j),
                pkfma(bc(x0), v2ld(w1 + HID   + j),
                pkfma(bc(x1), v2ld(w1 + 2*HID + j),
                pkfma(bc(x2), v2ld(w1 + 3*HID + j),
                pkfma(bc(p),  v2ld(w1 + 4*HID + j), v2ld(b1 + j))))));
        v2f h = fast_tanh2(z);
        o01 = pkfma(bc(h.x), v2ld(w2 + 2*j), pkfma(bc(h.y), v2ld(w2 + 2*j + 2), o01));
    }
    ur = o01.x; ui = o01.y;
}

// ---- Pass 1: phi prefix ----
__global__ void __launch_bounds__(256) k_phi(
    const float* __restrict__ X, const float* __restrict__ P,
    float* __restrict__ phi, float* __restrict__ phiF)
{
    int b = blockIdx.x*256 + threadIdx.x;
    double s = 0.0;
    for (int k = 0; k < NSTEPS; k++) {
        size_t idx = (size_t)k*BATCH + b;
        phi[idx] = (float)(DTf * s);
        float p = P[idx];
        const float* xp = X + idx*3;
        float x0 = xp[0], x1 = xp[1], x2 = xp[2];
        s += (double)p * (double)(x0*x0 + x1*x1 + x2*x2);
    }
    phiF[b] = (float)(DTf * s);
}

// ---- Pass 2: 2048-task window, 8 balanced passes per thread ----
// Compacted order (full tasks first) + slot pass*256+tid means every wave
// runs ~1/3 full-passes + ~2/3 jump-passes -> equal wave durations, no
// early-retire slot waste. Ballot-rank classification: 2 LDS atomics per
// wave per pass. Jump results are bit-identical in mixed vs pure paths,
// so nondeterministic placement still gives deterministic output.
__global__ void __launch_bounds__(BLKT) k_step(
    const float* __restrict__ N,  const float* __restrict__ X,
    const float* __restrict__ P,  const float* __restrict__ Tarr,
    const float* __restrict__ dB,
    const float* __restrict__ Wg1, const float* __restrict__ bg1,
    const float* __restrict__ Wg2, const float* __restrict__ bg2,
    const float* __restrict__ Wj1, const float* __restrict__ bj1,
    const float* __restrict__ Wj2, const float* __restrict__ bj2,
    const float* __restrict__ phiA, float* __restrict__ cA, float2* __restrict__ dA)
{
    int k = blockIdx.y;
    const float* w1  = Wg1 + k*5*HID;
    const float* b1  = bg1 + k*HID;
    const float* w2  = Wg2 + k*HID*6;
    const float* b2  = bg2 + k*6;
    const float* v1  = Wj1 + k*5*HID;
    const float* c1  = bj1 + k*HID;
    const float* vw2 = Wj2 + k*HID*2;
    float t = Tarr[k];

    __shared__ float Td[HID];
    __shared__ unsigned short sorig[WIN];
    __shared__ int cnt[2];
    if (threadIdx.x < HID) Td[threadIdx.x] = fast_tanh(v1[threadIdx.x]);
    if (threadIdx.x == 0) { cnt[0] = 0; cnt[1] = 0; }
    __syncthreads();

    int tid  = threadIdx.x;
    int lane = tid & 63;
    unsigned long long ltmask = ((unsigned long long)1 << lane) - 1;
    int base = blockIdx.x*WIN;

#pragma unroll
    for (int u = 0; u < PASSES; ++u) {
        int lb = u*BLKT + tid;                     // coalesced classify loads
        size_t i0 = (size_t)k*BATCH + base + lb;
        float dN0 = N[i0 + BATCH] - N[i0];         // exact +-1/0 in fp32
        bool f0 = (dN0 == 0.0f);
        unsigned long long m = __ballot(f0);
        int nf = __popcll(m);
        int rF = __popcll(m & ltmask);
        int rJ = lane - rF;
        int fb = 0, jb = 0;
        if (lane == 0) {
            fb = atomicAdd(&cnt[0], nf);
            jb = atomicAdd(&cnt[1], 64 - nf);
        }
        fb = __shfl(fb, 0);
        jb = __shfl(jb, 0);
        int pos = f0 ? (fb + rF) : (WIN - 1 - (jb + rJ));
        sorig[pos] = (unsigned short)lb;
    }
    __syncthreads();

    for (int pass = 0; pass < PASSES; ++pass) {
        int ob = base + sorig[pass*BLKT + tid];
        size_t idx = (size_t)k*BATCH + ob;
        float n  = N[idx], p = P[idx];
        float dN = N[idx + BATCH] - n;
        const float* xp = X + idx*3;
        float x0 = xp[0], x1 = xp[1], x2 = xp[2];
        float phi = phiA[idx];
        bool  g   = (dN == 0.0f);

        float c, sr, si;
        if (__ballot(g) != 0ull) {
            // ---- full / mixed wave ----
            const float* dbp = dB + idx*3;
            float db0 = dbp[0], db1 = dbp[1], db2 = dbp[2];
            float dup0, dup1, dum0, dum1;
            jump_mlp<true>(n,x0,x1,x2,p, v1,c1,vw2,Td, dup0,dup1,dum0,dum1);
            float og0, og1, og2, og3, og4, og5;
            grad_mlp(n,x0,x1,x2,p, w1,b1,w2,b2, og0,og1,og2,og3,og4,og5);

            float r2    = fmaf(x0,x0, fmaf(x1,x1, x2*x2));
            float gamma = 0.1f - (0.5f + 0.1f*r2) * __builtin_amdgcn_rcpf(1.0f + r2);
            float xdb   = fmaf(x0,db0, fmaf(x1,db1, x2*db2));
            float kc    = sqrtf(fmaf(0.2f, fabsf(n), 1.0f));
            float gdb_r = fmaf(og0,db0, fmaf(og1,db1, og2*db2));
            float gdb_i = fmaf(og3,db0, fmaf(og4,db1, og5*db2));
            float gx_r  = fmaf(og0,x0,  fmaf(og1,x1,  og2*x2));
            float gx_i  = fmaf(og3,x0,  fmaf(og4,x1,  og5*x2));
            float gb_r  = kc * fmaf(gamma*xdb, gx_r, 0.5f*gdb_r);
            float gb_i  = kc * fmaf(gamma*xdb, gx_i, 0.5f*gdb_i);

            float alpha = 0.5f*(n + 1.0f);
            float beta  = fmaf(0.4f, fabsf(n), 0.1f);
            float cf    = 0.1f*(1.0f + t)*DTf;
            float d0r = gb_r - (alpha*dup0 + beta*dum0)*DTf - cf*(og0+og1+og2);
            float d0i = gb_i - (alpha*dup1 + beta*dum1)*DTf - cf*(og3+og4+og5);

            if (dN > 0.5f)       { c = 1.0f;          sr = dup0; si = dup1; }
            else if (dN < -0.5f) { c = 1.0f;          sr = dum0; si = dum1; }
            else                 { c = 1.0f - p*DTf;  sr = d0r;  si = d0i;  }
        } else {
            // ---- pure jump wave: single-sided, no grad, no dB load ----
            jump_mlp_1s(n,x0,x1,x2,p, dN, v1,c1,vw2,Td, sr, si);
            c = 1.0f;
        }

        float sp, cp;
        __sincosf(phi, &sp, &cp);
        size_t oidx = (size_t)k*BATCH + ob;
        cA[oidx] = c;
        dA[oidx] = make_float2(fmaf(cp, sr,  sp*si), fmaf(cp, si, -sp*sr));
    }
}

// ---- Pass 3: u0 MLP + affine fold + g ----
__global__ void __launch_bounds__(256) k_combine(
    const float* __restrict__ N, const float* __restrict__ X, const float* __restrict__ P,
    const float* __restrict__ Wr1, const float* __restrict__ br1,
    const float* __restrict__ Wr2, const float* __restrict__ br2,
    const float* __restrict__ cA, const float2* __restrict__ dA,
    const float* __restrict__ phiF, float* __restrict__ out, int full)
{
    int b = blockIdx.x*256 + threadIdx.x;
    const float* xp = X + (size_t)b*3;
    float ur, ui;
    mlp_u0(N[b], xp[0], xp[1], xp[2], P[b], Wr1, br1, Wr2, br2, ur, ui);
#pragma unroll 8
    for (int k = 0; k < NSTEPS; k++) {
        size_t idx = (size_t)k*BATCH + b;
        float  c = cA[idx];
        float2 d = dA[idx];
        ur = fmaf(c, ur, d.x);
        ui = fmaf(c, ui, d.y);
    }
    float phi = phiF[b];
    const float* xf = X + ((size_t)NSTEPS*BATCH + b)*3;
    float s = xf[0] + xf[1] + xf[2];
    float sp, cp;
    __sincosf(phi, &sp, &cp);
    float gre =  s*cp;
    float gim = -s*sp;
    if (full) {
        out[b]           = ur;
        out[BATCH + b]   = ui;
        out[2*BATCH + b] = gre;
        out[3*BATCH + b] = gim;
    } else {
        out[b]         = ur;
        out[BATCH + b] = gre;
    }
}

// ---- Fallback (no workspace) ----
__global__ void __launch_bounds__(256) k_fused(
    const float* __restrict__ N,  const float* __restrict__ X,
    const float* __restrict__ P,  const float* __restrict__ Tarr,
    const float* __restrict__ dB,
    const float* __restrict__ Wr1, const float* __restrict__ br1,
    const float* __restrict__ Wr2, const float* __restrict__ br2,
    const float* __restrict__ Wg1, const float* __restrict__ bg1,
    const float* __restrict__ Wg2, const float* __restrict__ bg2,
    const float* __restrict__ Wj1, const float* __restrict__ bj1,
    const float* __restrict__ Wj2, const float* __restrict__ bj2,
    float* __restrict__ out, int full)
{
    int b = blockIdx.x*256 + threadIdx.x;
    float ur, ui;
    {
        const float* xp = X + (size_t)b*3;
        mlp_u0(N[b], xp[0], xp[1], xp[2], P[b], Wr1, br1, Wr2, br2, ur, ui);
    }
    double s = 0.0;
    for (int k = 0; k < NSTEPS; k++) {
        size_t idx = (size_t)k*BATCH + b;
        float n = N[idx], p = P[idx], t = Tarr[k];
        const float* xp  = X  + idx*3;
        const float* dbp = dB + idx*3;
        float dN  = N[idx + BATCH] - n;
        float phi = (float)(DTf * s);
        CD cd = step_core<false>(n, xp[0], xp[1], xp[2], p, t,
                                 dbp[0], dbp[1], dbp[2], dN, phi,
                                 Wg1 + k*5*HID, bg1 + k*HID,
                                 Wg2 + k*HID*6, bg2 + k*6,
                                 Wj1 + k*5*HID, bj1 + k*HID,
                                 Wj2 + k*HID*2, nullptr);
        ur = fmaf(cd.c, ur, cd.dre);
        ui = fmaf(cd.c, ui, cd.dim);
        float x0 = xp[0], x1 = xp[1], x2 = xp[2];
        s += (double)p * (double)(x0*x0 + x1*x1 + x2*x2);
    }
    float phi = (float)(DTf * s);
    const float* xf = X + ((size_t)NSTEPS*BATCH + b)*3;
    float sm = xf[0] + xf[1] + xf[2];
    float sp, cp;
    __sincosf(phi, &sp, &cp);
    float gre =  sm*cp;
    float gim = -sm*sp;
    if (full) {
        out[b]           = ur;
        out[BATCH + b]   = ui;
        out[2*BATCH + b] = gre;
        out[3*BATCH + b] = gim;
    } else {
        out[b]         = ur;
        out[BATCH + b] = gre;
    }
}

extern "C" void kernel_launch(void* const* d_in, const int* in_sizes, int n_in,
                              void* d_out, int out_size, void* d_ws, size_t ws_size,
                              hipStream_t stream)
{
    const float* N    = (const float*)d_in[0];
    const float* X    = (const float*)d_in[1];
    const float* P    = (const float*)d_in[2];
    const float* Tarr = (const float*)d_in[3];
    const float* dB   = (const float*)d_in[4];
    const float* Wr1  = (const float*)d_in[5];
    const float* br1  = (const float*)d_in[6];
    const float* Wr2  = (const float*)d_in[7];
    const float* br2  = (const float*)d_in[8];
    const float* Wg1  = (const float*)d_in[9];
    const float* bg1  = (const float*)d_in[10];
    const float* Wg2  = (const float*)d_in[11];
    const float* bg2  = (const float*)d_in[12];
    const float* Wj1  = (const float*)d_in[13];
    const float* bj1  = (const float*)d_in[14];
    const float* Wj2  = (const float*)d_in[15];
    const float* bj2  = (const float*)d_in[16];
    float* out = (float*)d_out;

    const int full = (out_size >= 4*BATCH) ? 1 : 0;

    const size_t phi_elems = (size_t)NSTEPS*BATCH;
    const size_t need = (phi_elems + BATCH + phi_elems)*sizeof(float)
                      + phi_elems*sizeof(float2);

    if (ws_size >= need) {
        float*  phiA = (float*)d_ws;
        float*  phiF = phiA + phi_elems;
        float*  cA   = phiF + BATCH;
        float2* dA   = (float2*)(cA + phi_elems);

        k_phi<<<dim3(BATCH/256), dim3(256), 0, stream>>>(X, P, phiA, phiF);
        k_step<<<dim3(BATCH/WIN, NSTEPS), dim3(BLKT), 0, stream>>>(
            N, X, P, Tarr, dB, Wg1, bg1, Wg2, bg2, Wj1, bj1, Wj2, bj2,
            phiA, cA, dA);
        k_combine<<<dim3(BATCH/256), dim3(256), 0, stream>>>(
            N, X, P, Wr1, br1, Wr2, br2, cA, dA, phiF, out, full);
    } else {
        k_fused<<<dim3(BATCH/256), dim3(256), 0, stream>>>(
            N, X, P, Tarr, dB, Wr1, br1, Wr2, br2,
            Wg1, bg1, Wg2, bg2, Wj1, bj1, Wj2, bj2, out, full);
    }
}